// Round 1
// 392.877 us; speedup vs baseline: 1.0207x; 1.0207x over previous
//
#include <hip/hip_runtime.h>

#define NUM_BINS 256
#define NPI (3*512*512)   // 786432 elements per image
#define TPB 256
#define MM_BLOCKS 16      // blocks per image for minmax & hist passes
#define NSUB 32           // LDS sub-histograms per block (2 lanes/wave per sub)
#define SUBSTRIDE 257     // 257 % 32 == 1: base bank of sub s is s -> spread
#define G_VEC 8           // float4 (= one packed uint of 4 bins) per thread per iter in gather

// Must bit-match the f32 reference: (v-mn)*255 / (mx-mn+1e-8), clip, trunc.
// Keep the real division — a reciprocal precompute shifts boundary bins.
__device__ __forceinline__ int bin_of(float v, float mn, float denom) {
  float norm = (v - mn) * 255.0f / denom;
  norm = fminf(fmaxf(norm, 0.0f), 255.0f);
  return (int)norm;
}

__device__ __forceinline__ unsigned pack4(int b0, int b1, int b2, int b3) {
  return (unsigned)b0 | ((unsigned)b1 << 8) | ((unsigned)b2 << 16) | ((unsigned)b3 << 24);
}

// Per-block min/max -> plain f32 slots. No atomics, no init kernel needed.
__global__ void minmax_k(const float4* __restrict__ x,
                         float* __restrict__ mmn, float* __restrict__ mmx) {
  const int chunk4 = NPI / 4 / MM_BLOCKS;  // 12288 float4 per block
  int img = blockIdx.x / MM_BLOCKS;
  int blk = blockIdx.x % MM_BLOCKS;
  const float4* p = x + (size_t)img * (NPI/4) + (size_t)blk * chunk4;
  float mn = 3.4e38f, mx = -3.4e38f;
  for (int i = threadIdx.x; i < chunk4; i += TPB) {
    float4 v = p[i];
    mn = fminf(mn, fminf(fminf(v.x, v.y), fminf(v.z, v.w)));
    mx = fmaxf(mx, fmaxf(fmaxf(v.x, v.y), fmaxf(v.z, v.w)));
  }
  for (int off = 32; off > 0; off >>= 1) {
    mn = fminf(mn, __shfl_down(mn, off));
    mx = fmaxf(mx, __shfl_down(mx, off));
  }
  __shared__ float smn[4], smx[4];
  int wave = threadIdx.x >> 6, lane = threadIdx.x & 63;
  if (lane == 0) { smn[wave] = mn; smx[wave] = mx; }
  __syncthreads();
  if (threadIdx.x == 0) {
    mmn[blockIdx.x] = fminf(fminf(smn[0], smn[1]), fminf(smn[2], smn[3]));
    mmx[blockIdx.x] = fmaxf(fmaxf(smx[0], smx[1]), fmaxf(smx[2], smx[3]));
  }
}

// Histogram into LDS sub-hists; per-block hist out (no global atomics).
// Also caches the uint8 bin index of every pixel (packed 4/uint) so the
// gather pass reads 50 MB instead of 201 MB and skips the division chain.
__global__ void hist_k(const float4* __restrict__ x,
                       const float* __restrict__ mmn, const float* __restrict__ mmx,
                       int* __restrict__ histblk, unsigned* __restrict__ bins32) {
  __shared__ int sh[NSUB * SUBSTRIDE];
  __shared__ float s_mn, s_dn;
  for (int i = threadIdx.x; i < NSUB * SUBSTRIDE; i += TPB) sh[i] = 0;
  const int chunk4 = NPI / 4 / MM_BLOCKS;  // 12288
  int img = blockIdx.x / MM_BLOCKS;
  int blk = blockIdx.x % MM_BLOCKS;
  if (threadIdx.x < MM_BLOCKS) {
    float a = mmn[img * MM_BLOCKS + threadIdx.x];
    float b = mmx[img * MM_BLOCKS + threadIdx.x];
    for (int off = 8; off > 0; off >>= 1) {
      a = fminf(a, __shfl_down(a, off));
      b = fmaxf(b, __shfl_down(b, off));
    }
    if (threadIdx.x == 0) { s_mn = a; s_dn = b - a + 1e-8f; }
  }
  __syncthreads();
  float mn = s_mn, denom = s_dn;
  size_t gbase = (size_t)img * (NPI/4) + (size_t)blk * chunk4;  // float4-index space
  const float4* p = x + gbase;
  int* mysub = sh + (threadIdx.x & (NSUB - 1)) * SUBSTRIDE;
  bool wb = (bins32 != nullptr);
  for (int i = threadIdx.x; i < chunk4; i += TPB * 4) {
    float4 v0 = p[i];
    float4 v1 = p[i + TPB];
    float4 v2 = p[i + 2*TPB];
    float4 v3 = p[i + 3*TPB];
    int b00 = bin_of(v0.x, mn, denom), b01 = bin_of(v0.y, mn, denom);
    int b02 = bin_of(v0.z, mn, denom), b03 = bin_of(v0.w, mn, denom);
    int b10 = bin_of(v1.x, mn, denom), b11 = bin_of(v1.y, mn, denom);
    int b12 = bin_of(v1.z, mn, denom), b13 = bin_of(v1.w, mn, denom);
    int b20 = bin_of(v2.x, mn, denom), b21 = bin_of(v2.y, mn, denom);
    int b22 = bin_of(v2.z, mn, denom), b23 = bin_of(v2.w, mn, denom);
    int b30 = bin_of(v3.x, mn, denom), b31 = bin_of(v3.y, mn, denom);
    int b32 = bin_of(v3.z, mn, denom), b33 = bin_of(v3.w, mn, denom);
    atomicAdd(&mysub[b00], 1); atomicAdd(&mysub[b01], 1);
    atomicAdd(&mysub[b02], 1); atomicAdd(&mysub[b03], 1);
    atomicAdd(&mysub[b10], 1); atomicAdd(&mysub[b11], 1);
    atomicAdd(&mysub[b12], 1); atomicAdd(&mysub[b13], 1);
    atomicAdd(&mysub[b20], 1); atomicAdd(&mysub[b21], 1);
    atomicAdd(&mysub[b22], 1); atomicAdd(&mysub[b23], 1);
    atomicAdd(&mysub[b30], 1); atomicAdd(&mysub[b31], 1);
    atomicAdd(&mysub[b32], 1); atomicAdd(&mysub[b33], 1);
    if (wb) {
      bins32[gbase + i]           = pack4(b00, b01, b02, b03);
      bins32[gbase + i + TPB]     = pack4(b10, b11, b12, b13);
      bins32[gbase + i + 2*TPB]   = pack4(b20, b21, b22, b23);
      bins32[gbase + i + 3*TPB]   = pack4(b30, b31, b32, b33);
    }
  }
  __syncthreads();
  int bin = threadIdx.x;
  int s = 0;
  #pragma unroll
  for (int c = 0; c < NSUB; ++c) s += sh[c * SUBSTRIDE + bin];
  histblk[blockIdx.x * NUM_BINS + bin] = s;  // coalesced, no atomic
}

__global__ void scan_k(const int* __restrict__ histblk, float* __restrict__ cdfn) {
  __shared__ int s[NUM_BINS];
  int img = blockIdx.x, t = threadIdx.x;
  int v = 0;
  #pragma unroll
  for (int b = 0; b < MM_BLOCKS; ++b)
    v += histblk[(img * MM_BLOCKS + b) * NUM_BINS + t];
  s[t] = v;
  __syncthreads();
  for (int off = 1; off < NUM_BINS; off <<= 1) {
    int add = (t >= off) ? s[t - off] : 0;
    __syncthreads();
    s[t] += add;
    __syncthreads();
  }
  int cdf = s[t], c0 = s[0], cN = s[NUM_BINS - 1];
  // counts are exact integers < 2^24, so int math == the reference's f32 cumsum
  cdfn[img * NUM_BINS + t] = (float)(cdf - c0) / ((float)(cN - c0) + 1e-8f);
}

// Fast gather: reads packed uint8 bins (4x less traffic, no division).
__global__ void gather_bins_k(const unsigned* __restrict__ bins32,
                              const float* __restrict__ cdfn,
                              float4* __restrict__ out) {
  __shared__ float c[NUM_BINS];
  const int f4pi = NPI / 4;               // 196608
  const int CHUNK = TPB * G_VEC;          // 2048
  const int bpi = f4pi / CHUNK;           // 96 blocks per image
  int img = blockIdx.x / bpi;
  int blk = blockIdx.x % bpi;
  c[threadIdx.x] = cdfn[img * NUM_BINS + threadIdx.x];  // TPB==NUM_BINS
  __syncthreads();
  size_t base = (size_t)img * f4pi + (size_t)blk * CHUNK + threadIdx.x;
  unsigned bv[G_VEC];
  #pragma unroll
  for (int j = 0; j < G_VEC; ++j) bv[j] = bins32[base + (size_t)j * TPB];
  #pragma unroll
  for (int j = 0; j < G_VEC; ++j) {
    unsigned b = bv[j];
    float4 o;
    o.x = c[b & 255u];
    o.y = c[(b >> 8) & 255u];
    o.z = c[(b >> 16) & 255u];
    o.w = c[b >> 24];
    out[base + (size_t)j * TPB] = o;
  }
}

// Fallback gather (workspace too small for bin cache): re-reads x.
__global__ void gather_x_k(const float4* __restrict__ x,
                           const float* __restrict__ mmn, const float* __restrict__ mmx,
                           const float* __restrict__ cdfn,
                           float4* __restrict__ out) {
  __shared__ float c[NUM_BINS];
  __shared__ float s_mn, s_dn;
  const int f4pi = NPI / 4;
  const int CHUNK = TPB * 4;
  const int bpi = f4pi / CHUNK;           // 192
  int img = blockIdx.x / bpi;
  int blk = blockIdx.x % bpi;
  c[threadIdx.x] = cdfn[img * NUM_BINS + threadIdx.x];
  if (threadIdx.x < MM_BLOCKS) {
    float a = mmn[img * MM_BLOCKS + threadIdx.x];
    float b = mmx[img * MM_BLOCKS + threadIdx.x];
    for (int off = 8; off > 0; off >>= 1) {
      a = fminf(a, __shfl_down(a, off));
      b = fmaxf(b, __shfl_down(b, off));
    }
    if (threadIdx.x == 0) { s_mn = a; s_dn = b - a + 1e-8f; }
  }
  __syncthreads();
  float mn = s_mn, denom = s_dn;
  size_t base = (size_t)img * f4pi + (size_t)blk * CHUNK + threadIdx.x;
  #pragma unroll
  for (int j = 0; j < 4; ++j) {
    float4 v = x[base + (size_t)j * TPB];
    float4 o;
    o.x = c[bin_of(v.x, mn, denom)];
    o.y = c[bin_of(v.y, mn, denom)];
    o.z = c[bin_of(v.z, mn, denom)];
    o.w = c[bin_of(v.w, mn, denom)];
    out[base + (size_t)j * TPB] = o;
  }
}

extern "C" void kernel_launch(void* const* d_in, const int* in_sizes, int n_in,
                              void* d_out, int out_size, void* d_ws, size_t ws_size,
                              hipStream_t stream) {
  const float* x = (const float*)d_in[0];
  float* out = (float*)d_out;
  int B = in_sizes[0] / NPI;  // 64 images

  // workspace layout:
  //   mmn:    B*16 f32        (per-block mins)
  //   mmx:    B*16 f32        (per-block maxs)
  //   histblk B*16*256 i32    (per-block histograms)
  //   cdfn:   B*256 f32
  //   bins:   B*NPI u8        (packed bin cache, optional)
  char* ws = (char*)d_ws;
  float* mmn = (float*)ws;
  float* mmx = mmn + (size_t)B * MM_BLOCKS;
  int* histblk = (int*)(mmx + (size_t)B * MM_BLOCKS);
  float* cdfn = (float*)(histblk + (size_t)B * MM_BLOCKS * NUM_BINS);
  unsigned* bins32 = (unsigned*)(cdfn + (size_t)B * NUM_BINS);
  size_t need = (size_t)((char*)bins32 - ws) + (size_t)B * NPI;
  bool use_bins = (ws_size >= need);

  minmax_k<<<B * MM_BLOCKS, TPB, 0, stream>>>((const float4*)x, mmn, mmx);
  hist_k<<<B * MM_BLOCKS, TPB, 0, stream>>>((const float4*)x, mmn, mmx, histblk,
                                            use_bins ? bins32 : nullptr);
  scan_k<<<B, NUM_BINS, 0, stream>>>(histblk, cdfn);
  if (use_bins) {
    gather_bins_k<<<B * (NPI/4/(TPB*G_VEC)), TPB, 0, stream>>>(bins32, cdfn, (float4*)out);
  } else {
    gather_x_k<<<B * (NPI/4/(TPB*4)), TPB, 0, stream>>>((const float4*)x, mmn, mmx, cdfn,
                                                        (float4*)out);
  }
}